// Round 23
// baseline (868.229 us; speedup 1.0000x reference)
//
#include <hip/hip_runtime.h>

#define B_SZ 4096
#define DM   768
#define DS   24576
#define TOPK 32
#define MAXC 512
#define NKT  (DM / 64)   // 12 K-steps of 64
#define NPLN 384         // partial-max planes: 192 n-tiles x 2 wn-halves

typedef _Float16 half8 __attribute__((ext_vector_type(8)));
typedef float f32x4 __attribute__((ext_vector_type(4)));

typedef const __attribute__((address_space(1))) void* gas_ptr;
typedef __attribute__((address_space(3))) void* las_ptr;

static __device__ inline _Float16 hmax(_Float16 a, _Float16 b) { return a > b ? a : b; }

// ---------------- Kernel 0: fp32 -> fp16 K-step-local XOR-swizzle, A and W in one launch ----------------
__global__ void k_conv2(const float* __restrict__ srcA, _Float16* __restrict__ dstA,
                        const float* __restrict__ srcW, _Float16* __restrict__ dstW) {
  int t = blockIdx.x * 256 + threadIdx.x;  // one 8-half block per thread
  const int nA = B_SZ * (DM / 8);
  const int nW = DS * (DM / 8);
  const float* src;
  _Float16* dst;
  if (t < nA) {
    src = srcA; dst = dstA;
  } else {
    t -= nA;
    if (t >= nW) return;
    src = srcW; dst = dstW;
  }
  int row = t / (DM / 8);
  int g = t % (DM / 8);
  int kt = g >> 3;
  int j = g & 7;
  int jd = j ^ (row & 7);
  const float* s = src + (size_t)row * DM + kt * 64 + j * 8;
  float4 a = *reinterpret_cast<const float4*>(s);
  float4 b = *reinterpret_cast<const float4*>(s + 4);
  half8 h;
  h[0] = (_Float16)a.x; h[1] = (_Float16)a.y; h[2] = (_Float16)a.z; h[3] = (_Float16)a.w;
  h[4] = (_Float16)b.x; h[5] = (_Float16)b.y; h[6] = (_Float16)b.z; h[7] = (_Float16)b.w;
  *reinterpret_cast<half8*>(dst + (size_t)row * DM + kt * 64 + jd * 8) = h;
}

// ---------------- Kernel 1: pre16 = fp16(A @ Wenc^T + b) + race-free row-max partials ----------------
__global__ __launch_bounds__(256, 2) void k_gemm16(const _Float16* __restrict__ A16,
                                                   const _Float16* __restrict__ W16,
                                                   const float* __restrict__ bias,
                                                   _Float16* __restrict__ pre,
                                                   float* __restrict__ partials) {
  __shared__ _Float16 SH[2 * 128 * 64];  // staging A|B; reused as C[128][128] in epilogue
  _Float16* Asl = SH;
  _Float16* Bsl = SH + 128 * 64;

  const int bid = blockIdx.x;
  const int sbid = (bid & 7) * 768 + (bid >> 3);  // XCD-contiguous chunks
  const int m0 = (sbid & 31) * 128;               // m fastest within an XCD
  const int n0 = (sbid >> 5) * 128;

  const int tid = threadIdx.x;
  const int lane = tid & 63;
  const int wid = tid >> 6;
  const int wm = (wid >> 1) * 64;
  const int wn = (wid & 1) * 64;

  f32x4 acc[4][4];
#pragma unroll
  for (int mi = 0; mi < 4; ++mi)
#pragma unroll
    for (int ni = 0; ni < 4; ++ni) acc[mi][ni] = (f32x4){0.f, 0.f, 0.f, 0.f};

  auto stage = [&](int kt) {
#pragma unroll
    for (int i = 0; i < 4; ++i) {
      const int c = tid + i * 256;
      const int row = c >> 3;
      const int seg = c & 7;
      const _Float16* ga = A16 + (size_t)(m0 + row) * DM + kt * 64 + seg * 8;
      const _Float16* gb = W16 + (size_t)(n0 + row) * DM + kt * 64 + seg * 8;
      _Float16* la = &Asl[(i * 256 + wid * 64) * 8];
      _Float16* lb = &Bsl[(i * 256 + wid * 64) * 8];
      __builtin_amdgcn_global_load_lds((gas_ptr)ga, (las_ptr)la, 16, 0, 0);
      __builtin_amdgcn_global_load_lds((gas_ptr)gb, (las_ptr)lb, 16, 0, 0);
    }
  };

  auto compute = [&]() {
#pragma unroll
    for (int ks = 0; ks < 2; ++ks) {
      half8 af[4], bf[4];
#pragma unroll
      for (int mi = 0; mi < 4; ++mi) {
        const int r = wm + mi * 16 + (lane & 15);
        const int byteoff = ((ks * 64 + (lane >> 4) * 16) ^ ((r & 7) << 4));
        af[mi] = *reinterpret_cast<const half8*>(reinterpret_cast<const char*>(Asl) + r * 128 + byteoff);
      }
#pragma unroll
      for (int ni = 0; ni < 4; ++ni) {
        const int r = wn + ni * 16 + (lane & 15);
        const int byteoff = ((ks * 64 + (lane >> 4) * 16) ^ ((r & 7) << 4));
        bf[ni] = *reinterpret_cast<const half8*>(reinterpret_cast<const char*>(Bsl) + r * 128 + byteoff);
      }
#pragma unroll
      for (int mi = 0; mi < 4; ++mi)
#pragma unroll
        for (int ni = 0; ni < 4; ++ni)
          acc[mi][ni] = __builtin_amdgcn_mfma_f32_16x16x32_f16(af[mi], bf[ni], acc[mi][ni], 0, 0, 0);
    }
  };

  stage(0);
#pragma unroll 1
  for (int kt = 0;; ++kt) {
    __syncthreads();
    compute();
    if (kt == NKT - 1) break;
    __syncthreads();
    stage(kt + 1);
  }
  __syncthreads();  // all waves done reading SH; safe to repurpose as C tile

  // ---- epilogue: bias + fp16, fragments -> SH[128][128], track per-row max ----
  const int cn0 = wn + (lane & 15);
  const int rb = wm + (lane >> 4) * 4;
  float bvv[4];
#pragma unroll
  for (int ni = 0; ni < 4; ++ni) bvv[ni] = bias[n0 + cn0 + ni * 16];

  float rmax[16];
#pragma unroll
  for (int mi = 0; mi < 4; ++mi)
#pragma unroll
    for (int r = 0; r < 4; ++r) {
      const int row = rb + mi * 16 + r;
      float p0 = acc[mi][0][r] + bvv[0];
      float p1 = acc[mi][1][r] + bvv[1];
      float p2 = acc[mi][2][r] + bvv[2];
      float p3 = acc[mi][3][r] + bvv[3];
      _Float16* c = SH + row * 128 + cn0;
      c[0]  = (_Float16)p0;
      c[16] = (_Float16)p1;
      c[32] = (_Float16)p2;
      c[48] = (_Float16)p3;
      rmax[mi * 4 + r] = fmaxf(fmaxf(p0, p1), fmaxf(p2, p3));
    }

#pragma unroll
  for (int q = 0; q < 16; ++q) {
    float v = rmax[q];
    v = fmaxf(v, __shfl_xor(v, 1));
    v = fmaxf(v, __shfl_xor(v, 2));
    v = fmaxf(v, __shfl_xor(v, 4));
    v = fmaxf(v, __shfl_xor(v, 8));
    rmax[q] = v;
  }
  const int plane = (n0 >> 7) * 2 + (wn >> 6);
  if ((lane & 15) == 0) {
#pragma unroll
    for (int q = 0; q < 16; ++q) {
      const int row = m0 + rb + (q >> 2) * 16 + (q & 3);
      partials[(size_t)plane * B_SZ + row] = rmax[q];
    }
  }
  __syncthreads();  // SH tile fully written

  // ---- coalesced copy-out (non-temporal): lanes 0..15 cover one row's 256B ----
  const int corow = tid >> 4;
  const int cchunk = tid & 15;
#pragma unroll
  for (int it = 0; it < 8; ++it) {
    const int row = it * 16 + corow;
    half8 vv = *reinterpret_cast<const half8*>(SH + row * 128 + cchunk * 8);
    __builtin_nontemporal_store(vv,
        reinterpret_cast<half8*>(pre + (size_t)(m0 + row) * DS + n0 + cchunk * 8));
  }
}

// ---------------- Kernel 2: two-phase per-row top-32 + fp64 refinement ----------------
// FUSE: zero and scatter MERGED via an LDS index-bitmap (3 KB): after rank, set
// 32 bits, LDS-sync, then each thread writes its 24 f32x4 exactly once (zeros,
// or mixed vector with looked-up values on the <=32 flagged vectors). No
// store->store ordering -> NO post-write barrier -> blocks retire while stores
// drain (round-22 diagnosis: per-block vmcnt(0) drains serialized ~110us).
// Pass 1: histogram + 12-bit tail mask. Pass 2: flagged chunks only. fp64
// refine + exact rank (value desc, index asc) = jax.lax.top_k.
template <bool FUSE>
__global__ __launch_bounds__(256) void k_topk(const _Float16* __restrict__ pre,
                                              const float* __restrict__ partials,
                                              const float* __restrict__ A,
                                              const float* __restrict__ W,
                                              const float* __restrict__ bias,
                                              float* __restrict__ out0,
                                              float* __restrict__ latents) {
  const int b = blockIdx.x;
  const int tid = threadIdx.x;
  __shared__ float swred[4];
  __shared__ int hist[128];
  __shared__ float sCollectLo;
  __shared__ int sNeedCoarse;
  __shared__ int cnt;
  __shared__ int cidx[MAXC];
  __shared__ double cval[MAXC];
  __shared__ float rvalS[TOPK];
  __shared__ int ridxS[TOPK];
  __shared__ unsigned bmap[DS / 32];  // 768 words = 3 KB scatter bitmap

  const _Float16* row = pre + (size_t)b * DS;

  float m = -1e30f;
  for (int i = tid; i < NPLN; i += 256) m = fmaxf(m, partials[(size_t)i * B_SZ + b]);
#pragma unroll
  for (int off = 32; off > 0; off >>= 1) m = fmaxf(m, __shfl_down(m, off));
  if ((tid & 63) == 0) swred[tid >> 6] = m;

  for (int i = tid; i < 128; i += 256) hist[i] = 0;
  for (int i = tid; i < DS / 32; i += 256) bmap[i] = 0u;
  if (tid == 0) cnt = 0;
  __syncthreads();
  const float rowMax = fmaxf(fmaxf(swred[0], swred[1]), fmaxf(swred[2], swred[3]));

  // ---- pass 1: histogram + tail mask (no collection) ----
  const float histLo = rowMax - 4.0f;
  const _Float16 histLoH = (_Float16)histLo;
  unsigned tailmask = 0;
#pragma unroll 1
  for (int i = 0; i < 12; ++i) {
    half8 v = *reinterpret_cast<const half8*>(row + (size_t)(tid + i * 256) * 8);
    _Float16 vm = hmax(hmax(hmax(v[0], v[1]), hmax(v[2], v[3])),
                       hmax(hmax(v[4], v[5]), hmax(v[6], v[7])));
    if (vm < histLoH) continue;  // vast majority of 16B chunks
    tailmask |= (1u << i);
#pragma unroll
    for (int j = 0; j < 8; ++j) {
      float vf = (float)v[j];
      if (vf >= histLo) {
        int bin = (int)((rowMax - vf) * 32.f);
        bin = bin < 0 ? 0 : (bin > 127 ? 127 : bin);
        atomicAdd(&hist[bin], 1);
      }
    }
  }
  __syncthreads();

  if (tid == 0) {
    int cum = 0, t = -1;
    for (int x = 0; x < 128; ++x) {
      cum += hist[x];
      if (cum >= TOPK) { t = x; break; }
    }
    if (t < 0) {
      sNeedCoarse = 1;
    } else {
      sNeedCoarse = 0;
      int mm = 127 - t; if (mm > 2) mm = 2;
      int c = cum;
      for (int y = t + 1; y <= t + mm; ++y) c += hist[y];
      while (mm > 0 && c > MAXC - 16) { c -= hist[t + mm]; --mm; }
      sCollectLo = rowMax - (float)(t + mm + 1) * (1.f / 32.f);  // >= histLo
    }
  }
  __syncthreads();

  if (sNeedCoarse) {
    // rare: coarse histogram (bins 1/2 over [rowMax-64, rowMax])
    for (int i = tid; i < 128; i += 256) hist[i] = 0;
    __syncthreads();
#pragma unroll 1
    for (int i = 0; i < 12; ++i) {
      half8 v = *reinterpret_cast<const half8*>(row + (size_t)(tid + i * 256) * 8);
#pragma unroll
      for (int j = 0; j < 8; ++j) {
        int bin = (int)((rowMax - (float)v[j]) * 2.f);
        bin = bin < 0 ? 0 : bin;
        if (bin < 128) atomicAdd(&hist[bin], 1);
      }
    }
    __syncthreads();
    if (tid == 0) {
      int cum = 0, t = -1;
      for (int x = 0; x < 128; ++x) {
        cum += hist[x];
        if (cum >= TOPK) { t = x; break; }
      }
      if (t < 0) {
        sCollectLo = -1e30f;  // degenerate guard: collect caps at MAXC
      } else {
        int mm = 127 - t; if (mm > 1) mm = 1;
        int c = cum;
        for (int y = t + 1; y <= t + mm; ++y) c += hist[y];
        while (mm > 0 && c > MAXC - 16) { c -= hist[t + mm]; --mm; }
        sCollectLo = rowMax - (float)(t + mm + 1) * 0.5f;
      }
    }
    __syncthreads();
  }

  // ---- pass 2: collect (bounded by construction) ----
  const float collectLo = sCollectLo;
  if (!sNeedCoarse) {
#pragma unroll 1
    for (int i = 0; i < 12; ++i) {
      if (!(tailmask & (1u << i))) continue;
      half8 v = *reinterpret_cast<const half8*>(row + (size_t)(tid + i * 256) * 8);
#pragma unroll
      for (int j = 0; j < 8; ++j) {
        float vf = (float)v[j];
        if (vf >= collectLo) {
          int p = atomicAdd(&cnt, 1);
          if (p < MAXC) cidx[p] = (tid + i * 256) * 8 + j;
        }
      }
    }
  } else {
#pragma unroll 1
    for (int i = 0; i < 12; ++i) {
      half8 v = *reinterpret_cast<const half8*>(row + (size_t)(tid + i * 256) * 8);
      _Float16 vm = hmax(hmax(hmax(v[0], v[1]), hmax(v[2], v[3])),
                         hmax(hmax(v[4], v[5]), hmax(v[6], v[7])));
      if ((float)vm < collectLo) continue;
#pragma unroll
      for (int j = 0; j < 8; ++j) {
        float vf = (float)v[j];
        if (vf >= collectLo) {
          int p = atomicAdd(&cnt, 1);
          if (p < MAXC) cidx[p] = (tid + i * 256) * 8 + j;
        }
      }
    }
  }
  __syncthreads();
  const int n = cnt < MAXC ? cnt : MAXC;

  // fp64 recompute of candidates (one wave per candidate, round-robin)
  const float* Ar = A + (size_t)b * DM;
  const int w = tid >> 6, lane = tid & 63;
  for (int c = w; c < n; c += 4) {
    const float* Wr = W + (size_t)cidx[c] * DM;
    double s = 0.0;
    for (int d = lane; d < DM; d += 64) s += (double)Ar[d] * (double)Wr[d];
#pragma unroll
    for (int off = 32; off > 0; off >>= 1) s += __shfl_down(s, off);
    if (lane == 0) cval[c] = s + (double)bias[cidx[c]];
  }
  __syncthreads();

  // exact rank (value desc, tie -> lower index); stash rank-ordered lists
  float* orow = out0 + (size_t)b * DM;
  for (int c = tid; c < n; c += 256) {
    double dv = cval[c];
    int di = cidx[c];
    int r = 0;
    for (int j = 0; j < n; ++j) {
      double o = cval[j];
      if (o > dv || (o == dv && cidx[j] < di)) ++r;
    }
    if (r < TOPK) {
      orow[r] = (float)dv;
      reinterpret_cast<int*>(orow)[TOPK + r] = di;
      rvalS[r] = (float)dv;
      ridxS[r] = di;
    }
  }

  if (FUSE) {
    __syncthreads();  // rvalS/ridxS complete
    if (tid < TOPK) {
      int idx = ridxS[tid];
      idx = idx < 0 ? 0 : (idx >= DS ? DS - 1 : idx);
      ridxS[tid] = idx;  // clamped for lookups below
      atomicOr(&bmap[idx >> 5], 1u << (idx & 31));
    }
    __syncthreads();  // bitmap ready (LDS-only dependency)
    // single write pass: zeros, or mixed vector on the <=32 flagged f32x4s.
    f32x4* lrow = reinterpret_cast<f32x4*>(latents + (size_t)b * DS);
    const f32x4 z = {0.f, 0.f, 0.f, 0.f};
#pragma unroll 1
    for (int i = 0; i < 24; ++i) {
      const int v4 = tid + i * 256;        // f32x4 index within the row
      const int e0 = v4 * 4;               // first element index
      unsigned mask4 = (bmap[e0 >> 5] >> (e0 & 31)) & 0xFu;  // e0 % 32 in {0,4,..,28}
      if (mask4 == 0u) {
        __builtin_nontemporal_store(z, lrow + v4);
      } else {
        f32x4 out = z;
#pragma unroll
        for (int e = 0; e < 4; ++e) {
          if (mask4 & (1u << e)) {
            const int gidx = e0 + e;
            float val = 0.f;
            for (int k = 0; k < TOPK; ++k)
              if (ridxS[k] == gidx) val = rvalS[k];
            out[e] = val;
          }
        }
        __builtin_nontemporal_store(out, lrow + v4);
      }
    }
    // no trailing barrier: stores drain while the block retires
  }
}

// ---------------- Kernel 3: fused zero + scatter (fallback when ws too small) ----------------
__global__ __launch_bounds__(256) void k_zscatter(const float* __restrict__ out0,
                                                  float* __restrict__ latents) {
  const int b = blockIdx.x;
  __shared__ float sval[TOPK];
  __shared__ int sidx[TOPK];
  const float* orow = out0 + (size_t)b * DM;
  if (threadIdx.x < TOPK) {
    sval[threadIdx.x] = orow[threadIdx.x];
    int idx = reinterpret_cast<const int*>(orow)[TOPK + threadIdx.x];
    sidx[threadIdx.x] = idx < 0 ? 0 : (idx >= DS ? DS - 1 : idx);
  }
  f32x4* lrow = reinterpret_cast<f32x4*>(latents + (size_t)b * DS);
  const f32x4 z = {0.f, 0.f, 0.f, 0.f};
#pragma unroll
  for (int i = 0; i < 24; ++i) __builtin_nontemporal_store(z, lrow + threadIdx.x + i * 256);
  __syncthreads();
  if (threadIdx.x < TOPK)
    latents[(size_t)b * DS + sidx[threadIdx.x]] = sval[threadIdx.x];
}

// ---------------- Kernel 4a: transpose W_dec [DM][DS] fp32 -> WdT16 [DS][DM] fp16 ----------------
__global__ void k_transpose16(const float* __restrict__ in, _Float16* __restrict__ out) {
  __shared__ float t[32][33];
  int sx = blockIdx.x * 32 + threadIdx.x;
  int d0 = blockIdx.y * 32;
#pragma unroll
  for (int j = 0; j < 32; j += 8)
    t[threadIdx.y + j][threadIdx.x] = in[(size_t)(d0 + threadIdx.y + j) * DS + sx];
  __syncthreads();
  int dx = d0 + threadIdx.x;
  int s0 = blockIdx.x * 32;
#pragma unroll
  for (int j = 0; j < 32; j += 8)
    out[(size_t)(s0 + threadIdx.y + j) * DM + dx] = (_Float16)t[threadIdx.x][threadIdx.y + j];
}

// ---------------- Kernel 4b: decode with fp16 transposed W_dec (coalesced) ----------------
__global__ __launch_bounds__(256) void k_decode(const _Float16* __restrict__ WdT,
                                                float* __restrict__ out0) {
  const int b = blockIdx.x;
  __shared__ int sidx[TOPK];
  __shared__ float sval[TOPK];
  float* orow = out0 + (size_t)b * DM;
  if (threadIdx.x < TOPK) {
    sval[threadIdx.x] = orow[threadIdx.x];
    int idx = reinterpret_cast<const int*>(orow)[TOPK + threadIdx.x];
    sidx[threadIdx.x] = idx < 0 ? 0 : (idx >= DS ? DS - 1 : idx);
  }
  __syncthreads();
  const int d = threadIdx.x;
  float a0 = 0.f, a1 = 0.f, a2 = 0.f;
#pragma unroll
  for (int k = 0; k < TOPK; ++k) {
    const _Float16* wr = WdT + (size_t)sidx[k] * DM;
    float v = sval[k];
    a0 = fmaf(v, (float)wr[d], a0);
    a1 = fmaf(v, (float)wr[d + 256], a1);
    a2 = fmaf(v, (float)wr[d + 512], a2);
  }
  orow[d] = a0;
  orow[d + 256] = a1;
  orow[d + 512] = a2;
}

// ---------------- Kernel 4b': decode fallback without transpose (strided, fp32) ----------------
__global__ __launch_bounds__(256) void k_decode_slow(const float* __restrict__ Wd,
                                                     float* __restrict__ out0) {
  const int b = blockIdx.x;
  __shared__ int sidx[TOPK];
  __shared__ float sval[TOPK];
  float* orow = out0 + (size_t)b * DM;
  if (threadIdx.x < TOPK) {
    sval[threadIdx.x] = orow[threadIdx.x];
    int idx = reinterpret_cast<const int*>(orow)[TOPK + threadIdx.x];
    sidx[threadIdx.x] = idx < 0 ? 0 : (idx >= DS ? DS - 1 : idx);
  }
  __syncthreads();
  const int d = threadIdx.x;
  float a0 = 0.f, a1 = 0.f, a2 = 0.f;
#pragma unroll
  for (int k = 0; k < TOPK; ++k) {
    float v = sval[k];
    a0 = fmaf(v, Wd[(size_t)d * DS + sidx[k]], a0);
    a1 = fmaf(v, Wd[(size_t)(d + 256) * DS + sidx[k]], a1);
    a2 = fmaf(v, Wd[(size_t)(d + 512) * DS + sidx[k]], a2);
  }
  orow[d] = a0;
  orow[d + 256] = a1;
  orow[d + 512] = a2;
}

extern "C" void kernel_launch(void* const* d_in, const int* in_sizes, int n_in,
                              void* d_out, int out_size, void* d_ws, size_t ws_size,
                              hipStream_t stream) {
  const float* A    = (const float*)d_in[0];  // mlp_input [B][DM]
  const float* Wenc = (const float*)d_in[1];  // [DS][DM]
  const float* benc = (const float*)d_in[2];  // [DS]
  const float* Wdec = (const float*)d_in[3];  // [DM][DS]

  float* out0    = (float*)d_out;             // [B][DM]
  float* latents = out0 + (size_t)B_SZ * DM;  // [B][DS], 402.7 MB

  const size_t wdt16_bytes = (size_t)DS * DM * sizeof(_Float16);   //  37.7 MB
  const size_t pre_bytes   = (size_t)B_SZ * DS * sizeof(_Float16); // 201.3 MB
  const size_t a16_bytes   = (size_t)B_SZ * DM * sizeof(_Float16); //   6.3 MB
  const size_t w16_bytes   = (size_t)DS * DM * sizeof(_Float16);   //  37.7 MB
  const size_t par_bytes   = (size_t)NPLN * B_SZ * sizeof(float);  //   6.3 MB
  const bool ws_all = ws_size >= wdt16_bytes + pre_bytes + a16_bytes + w16_bytes + par_bytes;
  const bool big_ws = ws_size >= wdt16_bytes;

  _Float16 *pre16, *A16, *W16;
  float *partials;
  _Float16* WdT16 = (_Float16*)d_ws;
  if (ws_all) {
    // everything in d_ws: latents region stays clean -> fused topk zero+scatter
    pre16    = (_Float16*)((char*)d_ws + wdt16_bytes);
    A16      = (_Float16*)((char*)pre16 + pre_bytes);
    W16      = (_Float16*)((char*)A16 + a16_bytes);
    partials = (float*)((char*)W16 + w16_bytes);
  } else {
    // carve scratch from the latents output region (dead until zscatter)
    pre16    = (_Float16*)latents;
    A16      = pre16 + (size_t)B_SZ * DS;
    W16      = A16 + (size_t)B_SZ * DM;
    partials = (float*)(W16 + (size_t)DS * DM);
  }

  // 0. convert A and W_enc to swizzled fp16 (single launch)
  {
    const int nA = B_SZ * (DM / 8);
    const int nW = DS * (DM / 8);
    k_conv2<<<(nA + nW + 255) / 256, 256, 0, stream>>>(A, A16, Wenc, W16);
  }

  // 1. encode screening GEMM (fp16 MFMA, m-fastest order, NT copy-out) + row-max partials
  k_gemm16<<<(DS / 128) * (B_SZ / 128), 256, 0, stream>>>(A16, W16, benc, pre16, partials);

  // 2. per-row top-32 (bitmap-merged zero+scatter when ws allows)
  if (ws_all) {
    k_topk<true><<<B_SZ, 256, 0, stream>>>(pre16, partials, A, Wenc, benc, out0, latents);
  } else {
    k_topk<false><<<B_SZ, 256, 0, stream>>>(pre16, partials, A, Wenc, benc, out0, latents);
    k_zscatter<<<B_SZ, 256, 0, stream>>>(out0, latents);
  }

  // 3. decode (overwrites out0 after loading its lists)
  if (big_ws) {
    k_transpose16<<<dim3(DS / 32, DM / 32), dim3(32, 8), 0, stream>>>(Wdec, WdT16);
    k_decode<<<B_SZ, 256, 0, stream>>>(WdT16, out0);
  } else {
    k_decode_slow<<<B_SZ, 256, 0, stream>>>(Wdec, out0);
  }
}

// Round 24
// 495.037 us; speedup vs baseline: 1.7539x; 1.7539x over previous
//
#include <hip/hip_runtime.h>

#define B_SZ 4096
#define DM   768
#define DS   24576
#define TOPK 32
#define MAXC 512
#define NKT  (DM / 64)   // 12 K-steps of 64
#define NPLN 384         // partial-max planes: 192 n-tiles x 2 wn-halves

typedef _Float16 half8 __attribute__((ext_vector_type(8)));
typedef float f32x4 __attribute__((ext_vector_type(4)));

typedef const __attribute__((address_space(1))) void* gas_ptr;
typedef __attribute__((address_space(3))) void* las_ptr;

static __device__ inline _Float16 hmax(_Float16 a, _Float16 b) { return a > b ? a : b; }

// ---------------- Kernel 0: fp32 -> fp16 K-step-local XOR-swizzle, A and W in one launch ----------------
__global__ void k_conv2(const float* __restrict__ srcA, _Float16* __restrict__ dstA,
                        const float* __restrict__ srcW, _Float16* __restrict__ dstW) {
  int t = blockIdx.x * 256 + threadIdx.x;  // one 8-half block per thread
  const int nA = B_SZ * (DM / 8);
  const int nW = DS * (DM / 8);
  const float* src;
  _Float16* dst;
  if (t < nA) {
    src = srcA; dst = dstA;
  } else {
    t -= nA;
    if (t >= nW) return;
    src = srcW; dst = dstW;
  }
  int row = t / (DM / 8);
  int g = t % (DM / 8);
  int kt = g >> 3;
  int j = g & 7;
  int jd = j ^ (row & 7);
  const float* s = src + (size_t)row * DM + kt * 64 + j * 8;
  float4 a = *reinterpret_cast<const float4*>(s);
  float4 b = *reinterpret_cast<const float4*>(s + 4);
  half8 h;
  h[0] = (_Float16)a.x; h[1] = (_Float16)a.y; h[2] = (_Float16)a.z; h[3] = (_Float16)a.w;
  h[4] = (_Float16)b.x; h[5] = (_Float16)b.y; h[6] = (_Float16)b.z; h[7] = (_Float16)b.w;
  *reinterpret_cast<half8*>(dst + (size_t)row * DM + kt * 64 + jd * 8) = h;
}

// ---------------- Kernel 1: pre16 = fp16(A @ Wenc^T + b) + race-free row-max partials ----------------
__global__ __launch_bounds__(256, 2) void k_gemm16(const _Float16* __restrict__ A16,
                                                   const _Float16* __restrict__ W16,
                                                   const float* __restrict__ bias,
                                                   _Float16* __restrict__ pre,
                                                   float* __restrict__ partials) {
  __shared__ _Float16 SH[2 * 128 * 64];  // staging A|B; reused as C[128][128] in epilogue
  _Float16* Asl = SH;
  _Float16* Bsl = SH + 128 * 64;

  const int bid = blockIdx.x;
  const int sbid = (bid & 7) * 768 + (bid >> 3);  // XCD-contiguous chunks
  const int m0 = (sbid & 31) * 128;               // m fastest within an XCD
  const int n0 = (sbid >> 5) * 128;

  const int tid = threadIdx.x;
  const int lane = tid & 63;
  const int wid = tid >> 6;
  const int wm = (wid >> 1) * 64;
  const int wn = (wid & 1) * 64;

  f32x4 acc[4][4];
#pragma unroll
  for (int mi = 0; mi < 4; ++mi)
#pragma unroll
    for (int ni = 0; ni < 4; ++ni) acc[mi][ni] = (f32x4){0.f, 0.f, 0.f, 0.f};

  auto stage = [&](int kt) {
#pragma unroll
    for (int i = 0; i < 4; ++i) {
      const int c = tid + i * 256;
      const int row = c >> 3;
      const int seg = c & 7;
      const _Float16* ga = A16 + (size_t)(m0 + row) * DM + kt * 64 + seg * 8;
      const _Float16* gb = W16 + (size_t)(n0 + row) * DM + kt * 64 + seg * 8;
      _Float16* la = &Asl[(i * 256 + wid * 64) * 8];
      _Float16* lb = &Bsl[(i * 256 + wid * 64) * 8];
      __builtin_amdgcn_global_load_lds((gas_ptr)ga, (las_ptr)la, 16, 0, 0);
      __builtin_amdgcn_global_load_lds((gas_ptr)gb, (las_ptr)lb, 16, 0, 0);
    }
  };

  auto compute = [&]() {
#pragma unroll
    for (int ks = 0; ks < 2; ++ks) {
      half8 af[4], bf[4];
#pragma unroll
      for (int mi = 0; mi < 4; ++mi) {
        const int r = wm + mi * 16 + (lane & 15);
        const int byteoff = ((ks * 64 + (lane >> 4) * 16) ^ ((r & 7) << 4));
        af[mi] = *reinterpret_cast<const half8*>(reinterpret_cast<const char*>(Asl) + r * 128 + byteoff);
      }
#pragma unroll
      for (int ni = 0; ni < 4; ++ni) {
        const int r = wn + ni * 16 + (lane & 15);
        const int byteoff = ((ks * 64 + (lane >> 4) * 16) ^ ((r & 7) << 4));
        bf[ni] = *reinterpret_cast<const half8*>(reinterpret_cast<const char*>(Bsl) + r * 128 + byteoff);
      }
#pragma unroll
      for (int mi = 0; mi < 4; ++mi)
#pragma unroll
        for (int ni = 0; ni < 4; ++ni)
          acc[mi][ni] = __builtin_amdgcn_mfma_f32_16x16x32_f16(af[mi], bf[ni], acc[mi][ni], 0, 0, 0);
    }
  };

  stage(0);
#pragma unroll 1
  for (int kt = 0;; ++kt) {
    __syncthreads();
    compute();
    if (kt == NKT - 1) break;
    __syncthreads();
    stage(kt + 1);
  }
  __syncthreads();  // all waves done reading SH; safe to repurpose as C tile

  // ---- epilogue: bias + fp16, fragments -> SH[128][128], track per-row max ----
  const int cn0 = wn + (lane & 15);
  const int rb = wm + (lane >> 4) * 4;
  float bvv[4];
#pragma unroll
  for (int ni = 0; ni < 4; ++ni) bvv[ni] = bias[n0 + cn0 + ni * 16];

  float rmax[16];
#pragma unroll
  for (int mi = 0; mi < 4; ++mi)
#pragma unroll
    for (int r = 0; r < 4; ++r) {
      const int row = rb + mi * 16 + r;
      float p0 = acc[mi][0][r] + bvv[0];
      float p1 = acc[mi][1][r] + bvv[1];
      float p2 = acc[mi][2][r] + bvv[2];
      float p3 = acc[mi][3][r] + bvv[3];
      _Float16* c = SH + row * 128 + cn0;
      c[0]  = (_Float16)p0;
      c[16] = (_Float16)p1;
      c[32] = (_Float16)p2;
      c[48] = (_Float16)p3;
      rmax[mi * 4 + r] = fmaxf(fmaxf(p0, p1), fmaxf(p2, p3));
    }

#pragma unroll
  for (int q = 0; q < 16; ++q) {
    float v = rmax[q];
    v = fmaxf(v, __shfl_xor(v, 1));
    v = fmaxf(v, __shfl_xor(v, 2));
    v = fmaxf(v, __shfl_xor(v, 4));
    v = fmaxf(v, __shfl_xor(v, 8));
    rmax[q] = v;
  }
  const int plane = (n0 >> 7) * 2 + (wn >> 6);
  if ((lane & 15) == 0) {
#pragma unroll
    for (int q = 0; q < 16; ++q) {
      const int row = m0 + rb + (q >> 2) * 16 + (q & 3);
      partials[(size_t)plane * B_SZ + row] = rmax[q];
    }
  }
  __syncthreads();  // SH tile fully written

  // ---- coalesced copy-out (non-temporal): lanes 0..15 cover one row's 256B ----
  const int corow = tid >> 4;
  const int cchunk = tid & 15;
#pragma unroll
  for (int it = 0; it < 8; ++it) {
    const int row = it * 16 + corow;
    half8 vv = *reinterpret_cast<const half8*>(SH + row * 128 + cchunk * 8);
    __builtin_nontemporal_store(vv,
        reinterpret_cast<half8*>(pre + (size_t)(m0 + row) * DS + n0 + cchunk * 8));
  }
}

// ---------------- Kernel 2: two-phase per-row top-32 + fp64 refinement ----------------
// FUSE: ZERO-FILL ONLY at the end, NO barriers around it (no data dependence;
// blocks retire while NT stores drain — kernel boundary guarantees visibility).
// The 32-element scatter moved to k_scat (next launch). Pass 1: histogram +
// 12-bit tail mask (4-deep pipelined loads). Pass 2: flagged chunks only.
// fp64 refine + exact rank (value desc, index asc) = jax.lax.top_k.
template <bool FUSE>
__global__ __launch_bounds__(256) void k_topk(const _Float16* __restrict__ pre,
                                              const float* __restrict__ partials,
                                              const float* __restrict__ A,
                                              const float* __restrict__ W,
                                              const float* __restrict__ bias,
                                              float* __restrict__ out0,
                                              float* __restrict__ latents) {
  const int b = blockIdx.x;
  const int tid = threadIdx.x;
  __shared__ float swred[4];
  __shared__ int hist[128];
  __shared__ float sCollectLo;
  __shared__ int sNeedCoarse;
  __shared__ int cnt;
  __shared__ int cidx[MAXC];
  __shared__ double cval[MAXC];

  const _Float16* row = pre + (size_t)b * DS;

  float m = -1e30f;
  for (int i = tid; i < NPLN; i += 256) m = fmaxf(m, partials[(size_t)i * B_SZ + b]);
#pragma unroll
  for (int off = 32; off > 0; off >>= 1) m = fmaxf(m, __shfl_down(m, off));
  if ((tid & 63) == 0) swred[tid >> 6] = m;

  for (int i = tid; i < 128; i += 256) hist[i] = 0;
  if (tid == 0) cnt = 0;
  __syncthreads();
  const float rowMax = fmaxf(fmaxf(swred[0], swred[1]), fmaxf(swred[2], swred[3]));

  // ---- pass 1: 4-deep pipelined histogram + tail mask ----
  const float histLo = rowMax - 4.0f;
  const _Float16 histLoH = (_Float16)histLo;
  unsigned tailmask = 0;
#pragma unroll 1
  for (int ii = 0; ii < 3; ++ii) {
    half8 vb[4];
#pragma unroll
    for (int q = 0; q < 4; ++q)
      vb[q] = *reinterpret_cast<const half8*>(row + (size_t)(tid + (ii * 4 + q) * 256) * 8);
#pragma unroll
    for (int q = 0; q < 4; ++q) {
      const int i = ii * 4 + q;
      half8 v = vb[q];
      _Float16 vm = hmax(hmax(hmax(v[0], v[1]), hmax(v[2], v[3])),
                         hmax(hmax(v[4], v[5]), hmax(v[6], v[7])));
      if (vm < histLoH) continue;  // vast majority of 16B chunks
      tailmask |= (1u << i);
#pragma unroll
      for (int j = 0; j < 8; ++j) {
        float vf = (float)v[j];
        if (vf >= histLo) {
          int bin = (int)((rowMax - vf) * 32.f);
          bin = bin < 0 ? 0 : (bin > 127 ? 127 : bin);
          atomicAdd(&hist[bin], 1);
        }
      }
    }
  }
  __syncthreads();

  if (tid == 0) {
    int cum = 0, t = -1;
    for (int x = 0; x < 128; ++x) {
      cum += hist[x];
      if (cum >= TOPK) { t = x; break; }
    }
    if (t < 0) {
      sNeedCoarse = 1;
    } else {
      sNeedCoarse = 0;
      int mm = 127 - t; if (mm > 2) mm = 2;
      int c = cum;
      for (int y = t + 1; y <= t + mm; ++y) c += hist[y];
      while (mm > 0 && c > MAXC - 16) { c -= hist[t + mm]; --mm; }
      sCollectLo = rowMax - (float)(t + mm + 1) * (1.f / 32.f);  // >= histLo
    }
  }
  __syncthreads();

  if (sNeedCoarse) {
    // rare: coarse histogram (bins 1/2 over [rowMax-64, rowMax])
    for (int i = tid; i < 128; i += 256) hist[i] = 0;
    __syncthreads();
#pragma unroll 1
    for (int i = 0; i < 12; ++i) {
      half8 v = *reinterpret_cast<const half8*>(row + (size_t)(tid + i * 256) * 8);
#pragma unroll
      for (int j = 0; j < 8; ++j) {
        int bin = (int)((rowMax - (float)v[j]) * 2.f);
        bin = bin < 0 ? 0 : bin;
        if (bin < 128) atomicAdd(&hist[bin], 1);
      }
    }
    __syncthreads();
    if (tid == 0) {
      int cum = 0, t = -1;
      for (int x = 0; x < 128; ++x) {
        cum += hist[x];
        if (cum >= TOPK) { t = x; break; }
      }
      if (t < 0) {
        sCollectLo = -1e30f;  // degenerate guard: collect caps at MAXC
      } else {
        int mm = 127 - t; if (mm > 1) mm = 1;
        int c = cum;
        for (int y = t + 1; y <= t + mm; ++y) c += hist[y];
        while (mm > 0 && c > MAXC - 16) { c -= hist[t + mm]; --mm; }
        sCollectLo = rowMax - (float)(t + mm + 1) * 0.5f;
      }
    }
    __syncthreads();
  }

  // ---- pass 2: collect (bounded by construction) ----
  const float collectLo = sCollectLo;
  if (!sNeedCoarse) {
#pragma unroll 1
    for (int i = 0; i < 12; ++i) {
      if (!(tailmask & (1u << i))) continue;
      half8 v = *reinterpret_cast<const half8*>(row + (size_t)(tid + i * 256) * 8);
#pragma unroll
      for (int j = 0; j < 8; ++j) {
        float vf = (float)v[j];
        if (vf >= collectLo) {
          int p = atomicAdd(&cnt, 1);
          if (p < MAXC) cidx[p] = (tid + i * 256) * 8 + j;
        }
      }
    }
  } else {
#pragma unroll 1
    for (int i = 0; i < 12; ++i) {
      half8 v = *reinterpret_cast<const half8*>(row + (size_t)(tid + i * 256) * 8);
      _Float16 vm = hmax(hmax(hmax(v[0], v[1]), hmax(v[2], v[3])),
                         hmax(hmax(v[4], v[5]), hmax(v[6], v[7])));
      if ((float)vm < collectLo) continue;
#pragma unroll
      for (int j = 0; j < 8; ++j) {
        float vf = (float)v[j];
        if (vf >= collectLo) {
          int p = atomicAdd(&cnt, 1);
          if (p < MAXC) cidx[p] = (tid + i * 256) * 8 + j;
        }
      }
    }
  }
  __syncthreads();
  const int n = cnt < MAXC ? cnt : MAXC;

  // fp64 recompute of candidates (one wave per candidate, round-robin)
  const float* Ar = A + (size_t)b * DM;
  const int w = tid >> 6, lane = tid & 63;
  for (int c = w; c < n; c += 4) {
    const float* Wr = W + (size_t)cidx[c] * DM;
    double s = 0.0;
    for (int d = lane; d < DM; d += 64) s += (double)Ar[d] * (double)Wr[d];
#pragma unroll
    for (int off = 32; off > 0; off >>= 1) s += __shfl_down(s, off);
    if (lane == 0) cval[c] = s + (double)bias[cidx[c]];
  }
  __syncthreads();

  // exact rank (value desc, tie -> lower index)
  float* orow = out0 + (size_t)b * DM;
  for (int c = tid; c < n; c += 256) {
    double dv = cval[c];
    int di = cidx[c];
    int r = 0;
    for (int j = 0; j < n; ++j) {
      double o = cval[j];
      if (o > dv || (o == dv && cidx[j] < di)) ++r;
    }
    if (r < TOPK) {
      orow[r] = (float)dv;
      reinterpret_cast<int*>(orow)[TOPK + r] = di;
    }
  }

  if (FUSE) {
    // zero-fill only; NO barriers. Blocks retire while NT stores drain; the
    // kernel boundary makes zeros visible to k_scat. (round-23 bitmap variant
    // cost 104 VGPR / 22% occupancy — this keeps round-22's 24 VGPR.)
    f32x4* lrow = reinterpret_cast<f32x4*>(latents + (size_t)b * DS);
    const f32x4 z = {0.f, 0.f, 0.f, 0.f};
#pragma unroll
    for (int i = 0; i < 24; ++i) __builtin_nontemporal_store(z, lrow + tid + i * 256);
  }
}

// ---------------- Kernel 2b: scatter top-32 values (after zeros, before decode) ----------------
__global__ __launch_bounds__(256) void k_scat(const float* __restrict__ out0,
                                              float* __restrict__ latents) {
  int t = blockIdx.x * 256 + threadIdx.x;
  if (t >= B_SZ * TOPK) return;
  int b = t >> 5;
  int k = t & 31;
  const float* orow = out0 + (size_t)b * DM;
  int idx = reinterpret_cast<const int*>(orow)[TOPK + k];
  idx = idx < 0 ? 0 : (idx >= DS ? DS - 1 : idx);
  latents[(size_t)b * DS + idx] = orow[k];
}

// ---------------- Kernel 3: fused zero + scatter (fallback when ws too small) ----------------
__global__ __launch_bounds__(256) void k_zscatter(const float* __restrict__ out0,
                                                  float* __restrict__ latents) {
  const int b = blockIdx.x;
  __shared__ float sval[TOPK];
  __shared__ int sidx[TOPK];
  const float* orow = out0 + (size_t)b * DM;
  if (threadIdx.x < TOPK) {
    sval[threadIdx.x] = orow[threadIdx.x];
    int idx = reinterpret_cast<const int*>(orow)[TOPK + threadIdx.x];
    sidx[threadIdx.x] = idx < 0 ? 0 : (idx >= DS ? DS - 1 : idx);
  }
  f32x4* lrow = reinterpret_cast<f32x4*>(latents + (size_t)b * DS);
  const f32x4 z = {0.f, 0.f, 0.f, 0.f};
#pragma unroll
  for (int i = 0; i < 24; ++i) __builtin_nontemporal_store(z, lrow + threadIdx.x + i * 256);
  __syncthreads();
  if (threadIdx.x < TOPK)
    latents[(size_t)b * DS + sidx[threadIdx.x]] = sval[threadIdx.x];
}

// ---------------- Kernel 4a: transpose W_dec [DM][DS] fp32 -> WdT16 [DS][DM] fp16 ----------------
__global__ void k_transpose16(const float* __restrict__ in, _Float16* __restrict__ out) {
  __shared__ float t[32][33];
  int sx = blockIdx.x * 32 + threadIdx.x;
  int d0 = blockIdx.y * 32;
#pragma unroll
  for (int j = 0; j < 32; j += 8)
    t[threadIdx.y + j][threadIdx.x] = in[(size_t)(d0 + threadIdx.y + j) * DS + sx];
  __syncthreads();
  int dx = d0 + threadIdx.x;
  int s0 = blockIdx.x * 32;
#pragma unroll
  for (int j = 0; j < 32; j += 8)
    out[(size_t)(s0 + threadIdx.y + j) * DM + dx] = (_Float16)t[threadIdx.x][threadIdx.y + j];
}

// ---------------- Kernel 4b: decode with fp16 transposed W_dec (coalesced) ----------------
__global__ __launch_bounds__(256) void k_decode(const _Float16* __restrict__ WdT,
                                                float* __restrict__ out0) {
  const int b = blockIdx.x;
  __shared__ int sidx[TOPK];
  __shared__ float sval[TOPK];
  float* orow = out0 + (size_t)b * DM;
  if (threadIdx.x < TOPK) {
    sval[threadIdx.x] = orow[threadIdx.x];
    int idx = reinterpret_cast<const int*>(orow)[TOPK + threadIdx.x];
    sidx[threadIdx.x] = idx < 0 ? 0 : (idx >= DS ? DS - 1 : idx);
  }
  __syncthreads();
  const int d = threadIdx.x;
  float a0 = 0.f, a1 = 0.f, a2 = 0.f;
#pragma unroll
  for (int k = 0; k < TOPK; ++k) {
    const _Float16* wr = WdT + (size_t)sidx[k] * DM;
    float v = sval[k];
    a0 = fmaf(v, (float)wr[d], a0);
    a1 = fmaf(v, (float)wr[d + 256], a1);
    a2 = fmaf(v, (float)wr[d + 512], a2);
  }
  orow[d] = a0;
  orow[d + 256] = a1;
  orow[d + 512] = a2;
}

// ---------------- Kernel 4b': decode fallback without transpose (strided, fp32) ----------------
__global__ __launch_bounds__(256) void k_decode_slow(const float* __restrict__ Wd,
                                                     float* __restrict__ out0) {
  const int b = blockIdx.x;
  __shared__ int sidx[TOPK];
  __shared__ float sval[TOPK];
  float* orow = out0 + (size_t)b * DM;
  if (threadIdx.x < TOPK) {
    sval[threadIdx.x] = orow[threadIdx.x];
    int idx = reinterpret_cast<const int*>(orow)[TOPK + threadIdx.x];
    sidx[threadIdx.x] = idx < 0 ? 0 : (idx >= DS ? DS - 1 : idx);
  }
  __syncthreads();
  const int d = threadIdx.x;
  float a0 = 0.f, a1 = 0.f, a2 = 0.f;
#pragma unroll
  for (int k = 0; k < TOPK; ++k) {
    float v = sval[k];
    a0 = fmaf(v, Wd[(size_t)d * DS + sidx[k]], a0);
    a1 = fmaf(v, Wd[(size_t)(d + 256) * DS + sidx[k]], a1);
    a2 = fmaf(v, Wd[(size_t)(d + 512) * DS + sidx[k]], a2);
  }
  orow[d] = a0;
  orow[d + 256] = a1;
  orow[d + 512] = a2;
}

extern "C" void kernel_launch(void* const* d_in, const int* in_sizes, int n_in,
                              void* d_out, int out_size, void* d_ws, size_t ws_size,
                              hipStream_t stream) {
  const float* A    = (const float*)d_in[0];  // mlp_input [B][DM]
  const float* Wenc = (const float*)d_in[1];  // [DS][DM]
  const float* benc = (const float*)d_in[2];  // [DS]
  const float* Wdec = (const float*)d_in[3];  // [DM][DS]

  float* out0    = (float*)d_out;             // [B][DM]
  float* latents = out0 + (size_t)B_SZ * DM;  // [B][DS], 402.7 MB

  const size_t wdt16_bytes = (size_t)DS * DM * sizeof(_Float16);   //  37.7 MB
  const size_t pre_bytes   = (size_t)B_SZ * DS * sizeof(_Float16); // 201.3 MB
  const size_t a16_bytes   = (size_t)B_SZ * DM * sizeof(_Float16); //   6.3 MB
  const size_t w16_bytes   = (size_t)DS * DM * sizeof(_Float16);   //  37.7 MB
  const size_t par_bytes   = (size_t)NPLN * B_SZ * sizeof(float);  //   6.3 MB
  const bool ws_all = ws_size >= wdt16_bytes + pre_bytes + a16_bytes + w16_bytes + par_bytes;
  const bool big_ws = ws_size >= wdt16_bytes;

  _Float16 *pre16, *A16, *W16;
  float *partials;
  _Float16* WdT16 = (_Float16*)d_ws;
  if (ws_all) {
    // everything in d_ws: latents region stays clean -> zero-in-topk + k_scat
    pre16    = (_Float16*)((char*)d_ws + wdt16_bytes);
    A16      = (_Float16*)((char*)pre16 + pre_bytes);
    W16      = (_Float16*)((char*)A16 + a16_bytes);
    partials = (float*)((char*)W16 + w16_bytes);
  } else {
    // carve scratch from the latents output region (dead until zscatter)
    pre16    = (_Float16*)latents;
    A16      = pre16 + (size_t)B_SZ * DS;
    W16      = A16 + (size_t)B_SZ * DM;
    partials = (float*)(W16 + (size_t)DS * DM);
  }

  // 0. convert A and W_enc to swizzled fp16 (single launch)
  {
    const int nA = B_SZ * (DM / 8);
    const int nW = DS * (DM / 8);
    k_conv2<<<(nA + nW + 255) / 256, 256, 0, stream>>>(A, A16, Wenc, W16);
  }

  // 1. encode screening GEMM (fp16 MFMA, m-fastest order, NT copy-out) + row-max partials
  k_gemm16<<<(DS / 128) * (B_SZ / 128), 256, 0, stream>>>(A16, W16, benc, pre16, partials);

  // 2. per-row top-32; zero-fill barrier-free inside, scatter as its own launch
  if (ws_all) {
    k_topk<true><<<B_SZ, 256, 0, stream>>>(pre16, partials, A, Wenc, benc, out0, latents);
    k_scat<<<(B_SZ * TOPK + 255) / 256, 256, 0, stream>>>(out0, latents);
  } else {
    k_topk<false><<<B_SZ, 256, 0, stream>>>(pre16, partials, A, Wenc, benc, out0, latents);
    k_zscatter<<<B_SZ, 256, 0, stream>>>(out0, latents);
  }

  // 3. decode (overwrites out0 after loading its lists)
  if (big_ws) {
    k_transpose16<<<dim3(DS / 32, DM / 32), dim3(32, 8), 0, stream>>>(Wdec, WdT16);
    k_decode<<<B_SZ, 256, 0, stream>>>(WdT16, out0);
  } else {
    k_decode_slow<<<B_SZ, 256, 0, stream>>>(Wdec, out0);
  }
}